// Round 3
// baseline (97.798 us; speedup 1.0000x reference)
//
#include <hip/hip_runtime.h>

// feats [B=8, C=256, H=128, W=256] f32; labels [8,128,256] int32 in [0,19)
// out: means [19][256] then norm_means [19]  (4883 floats)
#define NCLS 19
#define NCH  256
#define HW   (128 * 256)
#define NPIX (8 * HW)            // 262144
#define P    32                  // pixels per tile
#define NT   (NPIX / P)          // 8192 tiles
#define PAD  33                  // bank = (c+p)&31 -> conflict-free columns
#define SUMS (NCLS * NCH)        // 4864
#define PN_NORM SUMS             // 4864..4882 per-class norm sums
#define PN_CNT  (SUMS + NCLS)    // 4883..4901 per-class counts
#define PSTRIDE 4928             // per-block partial stride (floats, 128B-mult)
#define GRID 512                 // 2 blocks/CU, 16 tiles/block

__global__ __launch_bounds__(256) void accum_kernel(
    const float* __restrict__ feats, const int* __restrict__ labels,
    float* __restrict__ partials)
{
    __shared__ float tile[NCH * PAD];
    __shared__ float accA[SUMS];     // even pixels (slot exclusive per thread)
    __shared__ float accB[SUMS];     // odd pixels
    __shared__ float accN[NCLS];
    __shared__ float accC[NCLS];
    __shared__ float sqred[8 * P];
    __shared__ int   lab_s[P];

    const int t = threadIdx.x;
    for (int j = t; j < SUMS; j += 256) { accA[j] = 0.f; accB[j] = 0.f; }
    if (t < NCLS) { accN[t] = 0.f; accC[t] = 0.f; }

    const int tiles = NT / GRID;               // 16
    const int tl0   = blockIdx.x * tiles;
    const int j4 = (t & 7) * 4, cb = t >> 3;   // stage layout: 8ch x 4px / thread

    float4 v4[8];
    int labv = 0;

    // ---- prologue: load + write tile 0 ----
    {
        const int p0 = tl0 * P, b = p0 / HW, hw0 = p0 % HW;
        const float* fb = feats + (size_t)b * NCH * HW + hw0;
        #pragma unroll
        for (int i = 0; i < 8; ++i)
            v4[i] = *reinterpret_cast<const float4*>(fb + (size_t)(i * 32 + cb) * HW + j4);
        if (t < P) labv = labels[p0 + t];
    }
    #pragma unroll
    for (int i = 0; i < 8; ++i) {
        const int c = i * 32 + cb;
        tile[c * PAD + j4    ] = v4[i].x; tile[c * PAD + j4 + 1] = v4[i].y;
        tile[c * PAD + j4 + 2] = v4[i].z; tile[c * PAD + j4 + 3] = v4[i].w;
    }
    if (t < P) lab_s[t] = labv;
    __syncthreads();

    for (int it = 0; it < tiles; ++it) {
        // ---- prefetch next tile into registers (overlaps compute below) ----
        if (it + 1 < tiles) {
            const int p0 = (tl0 + it + 1) * P, b = p0 / HW, hw0 = p0 % HW;
            const float* fb = feats + (size_t)b * NCH * HW + hw0;
            #pragma unroll
            for (int i = 0; i < 8; ++i)
                v4[i] = *reinterpret_cast<const float4*>(fb + (size_t)(i * 32 + cb) * HW + j4);
            if (t < P) labv = labels[p0 + t];
        }
        // ---- compute current tile from LDS ----
        {   // squared-norm partials: 8 groups x 32 px, (i+p)&31 banks: 2-way = free
            const int g = t >> 5, p = t & 31;
            float s = 0.f;
            #pragma unroll
            for (int i = 0; i < 32; ++i) { const float x = tile[(g * 32 + i) * PAD + p]; s += x * x; }
            sqred[g * 32 + p] = s;
        }
        {   // thread t owns channel t: exclusive-slot accumulate, no atomics
            float v[P];
            #pragma unroll
            for (int p = 0; p < P; ++p) v[p] = tile[t * PAD + p];
            #pragma unroll
            for (int p = 0; p < P; p += 2) {
                const int k0 = lab_s[p], k1 = lab_s[p + 1];
                accA[k0 * NCH + t] += v[p];
                accB[k1 * NCH + t] += v[p + 1];
            }
        }
        __syncthreads();   // tile fully read; sqred ready (vmcnt drain = after compute)
        if (t < P) {       // finish norms for current tile (reads OLD lab_s, then may overwrite)
            float s = 0.f;
            #pragma unroll
            for (int g = 0; g < 8; ++g) s += sqred[g * 32 + t];
            const int k = lab_s[t];
            unsafeAtomicAdd(&accN[k], sqrtf(s));
            unsafeAtomicAdd(&accC[k], 1.f);
        }
        if (it + 1 < tiles) {  // write prefetched tile (ds_write waits on its v4 deps only)
            #pragma unroll
            for (int i = 0; i < 8; ++i) {
                const int c = i * 32 + cb;
                tile[c * PAD + j4    ] = v4[i].x; tile[c * PAD + j4 + 1] = v4[i].y;
                tile[c * PAD + j4 + 2] = v4[i].z; tile[c * PAD + j4 + 3] = v4[i].w;
            }
            if (t < P) lab_s[t] = labv;
        }
        __syncthreads();
    }

    // ---- flush block partials (plain coalesced stores, output layout) ----
    float* op = partials + (size_t)blockIdx.x * PSTRIDE;
    for (int j = t; j < SUMS; j += 256) op[j] = accA[j] + accB[j];  // thread t reads own column
    if (t < NCLS) { op[PN_NORM + t] = accN[t]; op[PN_CNT + t] = accC[t]; }
}

__global__ __launch_bounds__(256) void reduce_kernel(
    const float* __restrict__ partials, float* __restrict__ out)
{
    const int o = blockIdx.x * 256 + threadIdx.x;
    if (o >= PN_CNT) return;                   // 4883 outputs
    const int k = (o < SUMS) ? (o >> 8) : (o - SUMS);
    float s = 0.f, c = 0.f;
    #pragma unroll 4
    for (int g = 0; g < GRID; ++g) {
        const float* p = partials + (size_t)g * PSTRIDE;
        s += p[o];                             // coalesced across lanes
        c += p[PN_CNT + k];                    // wave-uniform broadcast
    }
    out[o] = (c > 0.f) ? s / fmaxf(c, 1.f) : 0.f;
}

extern "C" void kernel_launch(void* const* d_in, const int* in_sizes, int n_in,
                              void* d_out, int out_size, void* d_ws, size_t ws_size,
                              hipStream_t stream) {
    const float* feats  = (const float*)d_in[0];
    const int*   labels = (const int*)d_in[1];
    float* out      = (float*)d_out;
    float* partials = (float*)d_ws;   // needs GRID*PSTRIDE*4 = 10.1 MB

    accum_kernel<<<GRID, 256, 0, stream>>>(feats, labels, partials);
    reduce_kernel<<<(PN_CNT + 255) / 256, 256, 0, stream>>>(partials, out);
}

// Round 4
// 65.343 us; speedup vs baseline: 1.4967x; 1.4967x over previous
//
#include <hip/hip_runtime.h>

// feats [B=8, C=256, H=128, W=256] f32; labels [8,128,256] int32 in [0,19)
// out: means [19][256] then norm_means [19]  (4883 floats)
#define NCLS 19
#define NCH  256
#define HW   (128 * 256)         // 32768, pow2
#define NPIX (8 * HW)            // 262144
#define P    32                  // pixels per tile
#define NT   (NPIX / P)          // 8192 tiles
#define TPAD 36                  // tile row stride: 144 B -> 16B-aligned rows (b128)
#define SPAD 33                  // sqpart row stride (conflict-free column reduce)
#define SUMS (NCLS * NCH)        // 4864
#define PN_NORM SUMS             // 4864..4882 per-class norm sums
#define PN_CNT  (SUMS + NCLS)    // 4883..4901 per-class counts
#define NSLOT   (SUMS + 2*NCLS)  // 4902
#define PSTRIDE 4928             // per-block partial stride (floats)
#define GRID  512                // 2 blocks/CU, grid-stride tiles
#define TILES (NT / GRID)        // 16

__global__ __launch_bounds__(256) void accum_kernel(
    const float* __restrict__ feats, const int* __restrict__ labels,
    float* __restrict__ partials)
{
    __shared__ float tile[NCH * TPAD];   // 36.9 KB
    __shared__ float accA[SUMS];         // even pixels (slot exclusive per thread)
    __shared__ float accB[SUMS];         // odd pixels          (2x19.46 KB)
    __shared__ float sqpart[32 * SPAD];  // 4.22 KB: [cb][px] sq partial over 8 ch
    __shared__ float accN[NCLS];
    __shared__ float accC[NCLS];
    __shared__ int   lab_s[P];           // total ~80.3 KB -> 2 blocks/CU

    const int t = threadIdx.x;
    for (int j = t; j < SUMS; j += 256) { accA[j] = 0.f; accB[j] = 0.f; }
    if (t < NCLS) { accN[t] = 0.f; accC[t] = 0.f; }

    const int j4 = (t & 7) * 4, cb = t >> 3;   // thread stages 8 ch x 4 px
    float4 v4[8];
    int labv = 0;

    // ---- prologue: load + write tile 0 ----
    {
        const int p0 = blockIdx.x * P, b = p0 >> 15, hw0 = p0 & (HW - 1);
        const float* fb = feats + (size_t)b * NCH * HW + hw0;
        #pragma unroll
        for (int i = 0; i < 8; ++i)
            v4[i] = *reinterpret_cast<const float4*>(fb + (size_t)(i * 32 + cb) * HW + j4);
        if (t < P) labv = labels[p0 + t];
    }
    {
        float s0 = 0.f, s1 = 0.f, s2 = 0.f, s3 = 0.f;
        #pragma unroll
        for (int i = 0; i < 8; ++i) {
            const int c = i * 32 + cb;
            tile[c * TPAD + j4    ] = v4[i].x; tile[c * TPAD + j4 + 1] = v4[i].y;
            tile[c * TPAD + j4 + 2] = v4[i].z; tile[c * TPAD + j4 + 3] = v4[i].w;
            s0 += v4[i].x * v4[i].x; s1 += v4[i].y * v4[i].y;
            s2 += v4[i].z * v4[i].z; s3 += v4[i].w * v4[i].w;
        }
        sqpart[cb * SPAD + j4    ] = s0; sqpart[cb * SPAD + j4 + 1] = s1;
        sqpart[cb * SPAD + j4 + 2] = s2; sqpart[cb * SPAD + j4 + 3] = s3;
        if (t < P) lab_s[t] = labv;
    }
    __syncthreads();

    for (int it = 0; it < TILES; ++it) {
        // A: issue next tile's loads (latency hides under B; drained at barrier)
        if (it + 1 < TILES) {
            const int p0 = (blockIdx.x + (it + 1) * GRID) * P;
            const int b = p0 >> 15, hw0 = p0 & (HW - 1);
            const float* fb = feats + (size_t)b * NCH * HW + hw0;
            #pragma unroll
            for (int i = 0; i < 8; ++i)
                v4[i] = *reinterpret_cast<const float4*>(fb + (size_t)(i * 32 + cb) * HW + j4);
            if (t < P) labv = labels[p0 + t];
        }
        // B: compute current tile from LDS (thread t owns channel t; no atomics)
        {
            float v[P];
            #pragma unroll
            for (int p = 0; p < P; ++p) v[p] = tile[t * TPAD + p];  // 8x ds_read_b128
            #pragma unroll
            for (int p = 0; p < P; p += 2) {
                const int k0 = lab_s[p], k1 = lab_s[p + 1];   // wave-uniform
                accA[k0 * NCH + t] += v[p];                   // two independent
                accB[k1 * NCH + t] += v[p + 1];               // RMW chains
            }
        }
        if (t < P) {   // finish norms for current tile (sqpart/lab_s hold current)
            float s = 0.f;
            #pragma unroll
            for (int m = 0; m < 32; ++m) s += sqpart[m * SPAD + t];  // conflict-free
            const int k = lab_s[t];
            unsafeAtomicAdd(&accN[k], sqrtf(s));
            unsafeAtomicAdd(&accC[k], 1.f);
        }
        __syncthreads();   // vmcnt drain lands here, after compute
        // D: write prefetched tile + in-register squares
        if (it + 1 < TILES) {
            float s0 = 0.f, s1 = 0.f, s2 = 0.f, s3 = 0.f;
            #pragma unroll
            for (int i = 0; i < 8; ++i) {
                const int c = i * 32 + cb;
                tile[c * TPAD + j4    ] = v4[i].x; tile[c * TPAD + j4 + 1] = v4[i].y;
                tile[c * TPAD + j4 + 2] = v4[i].z; tile[c * TPAD + j4 + 3] = v4[i].w;
                s0 += v4[i].x * v4[i].x; s1 += v4[i].y * v4[i].y;
                s2 += v4[i].z * v4[i].z; s3 += v4[i].w * v4[i].w;
            }
            sqpart[cb * SPAD + j4    ] = s0; sqpart[cb * SPAD + j4 + 1] = s1;
            sqpart[cb * SPAD + j4 + 2] = s2; sqpart[cb * SPAD + j4 + 3] = s3;
            if (t < P) lab_s[t] = labv;
        }
        __syncthreads();
    }

    // ---- flush block partials (plain coalesced stores) ----
    float* op = partials + (size_t)blockIdx.x * PSTRIDE;
    for (int j = t; j < SUMS; j += 256) op[j] = accA[j] + accB[j];
    if (t < NCLS) { op[PN_NORM + t] = accN[t]; op[PN_CNT + t] = accC[t]; }
}

// R1: reduce 512 group-partials -> raw sums for all 4902 slots.
// Block = 16 slots x 16 group-lanes; each lane sums 32 groups.
__global__ __launch_bounds__(256) void reduce1_kernel(
    const float* __restrict__ partials, float* __restrict__ sums)
{
    __shared__ float red[16][17];
    const int ol = threadIdx.x & 15, gl = threadIdx.x >> 4;
    const int o  = blockIdx.x * 16 + ol;
    float s = 0.f;
    if (o < NSLOT) {
        #pragma unroll 8
        for (int j = 0; j < 32; ++j)
            s += partials[(size_t)(gl + 16 * j) * PSTRIDE + o];
    }
    red[gl][ol] = s;
    __syncthreads();
    if (threadIdx.x < 16) {
        float tot = 0.f;
        #pragma unroll
        for (int g = 0; g < 16; ++g) tot += red[g][threadIdx.x];
        const int oo = blockIdx.x * 16 + threadIdx.x;
        if (oo < NSLOT) sums[oo] = tot;
    }
}

// R2: divide by counts, apply where(count>0, ..., 0)
__global__ __launch_bounds__(256) void reduce2_kernel(
    const float* __restrict__ sums, float* __restrict__ out)
{
    const int o = blockIdx.x * 256 + threadIdx.x;
    if (o >= PN_CNT) return;                    // 4883 outputs
    const int k = (o < SUMS) ? (o >> 8) : (o - SUMS);
    const float c = sums[PN_CNT + k];
    out[o] = (c > 0.f) ? sums[o] / fmaxf(c, 1.f) : 0.f;   // sums[o] valid for both ranges
}

extern "C" void kernel_launch(void* const* d_in, const int* in_sizes, int n_in,
                              void* d_out, int out_size, void* d_ws, size_t ws_size,
                              hipStream_t stream) {
    const float* feats  = (const float*)d_in[0];
    const int*   labels = (const int*)d_in[1];
    float* out      = (float*)d_out;
    float* partials = (float*)d_ws;                         // 512*4928*4 = 10.1 MB
    float* sums     = partials + (size_t)GRID * PSTRIDE;    // +19.6 KB

    accum_kernel<<<GRID, 256, 0, stream>>>(feats, labels, partials);
    reduce1_kernel<<<(NSLOT + 15) / 16, 256, 0, stream>>>(partials, sums);
    reduce2_kernel<<<(PN_CNT + 255) / 256, 256, 0, stream>>>(sums, out);
}